// Round 1
// baseline (1459.734 us; speedup 1.0000x reference)
//
#include <hip/hip_runtime.h>
#include <cstddef>

#define N_NODES 50000
#define N_EDGES 800000
#define N_GRAPHS 128
#define DIM 128
#define N_LAYERS 4
#define GN_EPS 1e-5f
#define MM_ROWS 64

// ---------------- histogram kernels ----------------
__global__ __launch_bounds__(256) void edge_hist(const int* __restrict__ dst, int* __restrict__ deg) {
    int e = blockIdx.x * 256 + threadIdx.x;
    if (e < N_EDGES) atomicAdd(&deg[dst[e]], 1);
}

__global__ __launch_bounds__(256) void node_hist(const int* __restrict__ batch, int* __restrict__ gcnt) {
    int i = blockIdx.x * 256 + threadIdx.x;
    if (i < N_NODES) atomicAdd(&gcnt[batch[i]], 1);
}

// ---------------- single-block exclusive scan (n up to ~64k) ----------------
__global__ __launch_bounds__(1024) void scan_excl(const int* __restrict__ in, int* __restrict__ out, int n) {
    __shared__ int sdata[1024];
    __shared__ int s_carry;
    int tid = threadIdx.x;
    if (tid == 0) s_carry = 0;
    __syncthreads();
    for (int base = 0; base < n; base += 1024) {
        int carry = s_carry;
        int v = (base + tid < n) ? in[base + tid] : 0;
        sdata[tid] = v;
        __syncthreads();
        for (int off = 1; off < 1024; off <<= 1) {
            int t = (tid >= off) ? sdata[tid - off] : 0;
            __syncthreads();
            sdata[tid] += t;
            __syncthreads();
        }
        if (base + tid < n) out[base + tid] = carry + sdata[tid] - v;
        int total = sdata[1023];
        __syncthreads();
        if (tid == 0) s_carry = carry + total;
        __syncthreads();
    }
    if (tid == 0) out[n] = s_carry;
}

// ---------------- CSR scatter ----------------
__global__ __launch_bounds__(256) void scatter_edges(const int* __restrict__ src, const int* __restrict__ dst,
                                                     const int* __restrict__ eoff, int* __restrict__ cursor,
                                                     int* __restrict__ csr) {
    int e = blockIdx.x * 256 + threadIdx.x;
    if (e < N_EDGES) {
        int d = dst[e];
        int pos = atomicAdd(&cursor[d], 1);
        csr[eoff[d] + pos] = src[e];
    }
}

// ---------------- GIN aggregation: t[i] = h[i] + sum_{j in in(i)} h[j] ----------------
// one wave (64 lanes) per node; lane owns dims lane and lane+64
__global__ __launch_bounds__(256) void agg_add(const float* __restrict__ h, const int* __restrict__ eoff,
                                               const int* __restrict__ csr, float* __restrict__ out) {
    int wid = (blockIdx.x * 256 + threadIdx.x) >> 6;
    int lane = threadIdx.x & 63;
    if (wid >= N_NODES) return;
    int lo = eoff[wid], hi = eoff[wid + 1];
    const float* hr = h + (size_t)wid * DIM;
    float a0 = hr[lane];
    float a1 = hr[lane + 64];
    for (int e = lo; e < hi; ++e) {
        int j = csr[e];
        const float* hj = h + (size_t)j * DIM;
        a0 += hj[lane];
        a1 += hj[lane + 64];
    }
    float* o = out + (size_t)wid * DIM;
    o[lane] = a0;
    o[lane + 64] = a1;
}

// ---------------- fp32 GEMM + bias + relu: C = relu(A @ W + b), A[n,128], W[128,128] ----------------
__global__ __launch_bounds__(256) void mm_relu(const float* __restrict__ Ain, const float* __restrict__ W,
                                               const float* __restrict__ bias, float* __restrict__ Cout, int nrows) {
    __shared__ float Wl[DIM * DIM];       // 64 KB
    __shared__ float Al[MM_ROWS * DIM];   // 32 KB
    int tid = threadIdx.x;
    const float4* W4 = (const float4*)W;
    float4* Wl4 = (float4*)Wl;
    #pragma unroll
    for (int i = 0; i < 16; ++i) Wl4[tid + i * 256] = W4[tid + i * 256];  // 4096 float4

    int row0 = blockIdx.x * MM_ROWS;
    int ntile = nrows - row0;
    if (ntile > MM_ROWS) ntile = MM_ROWS;
    const float4* A4 = (const float4*)(Ain + (size_t)row0 * DIM);
    float4* Al4 = (float4*)Al;
    for (int i = tid; i < ntile * (DIM / 4); i += 256) Al4[i] = A4[i];
    __syncthreads();

    int cg = (tid & 31) * 4;   // 4 columns
    int rg = (tid >> 5) * 8;   // 8 rows
    float4 acc[8];
    #pragma unroll
    for (int r = 0; r < 8; ++r) acc[r] = make_float4(0.f, 0.f, 0.f, 0.f);

    for (int k = 0; k < DIM; k += 4) {
        float4 w0 = *(const float4*)&Wl[(k + 0) * DIM + cg];
        float4 w1 = *(const float4*)&Wl[(k + 1) * DIM + cg];
        float4 w2 = *(const float4*)&Wl[(k + 2) * DIM + cg];
        float4 w3 = *(const float4*)&Wl[(k + 3) * DIM + cg];
        #pragma unroll
        for (int r = 0; r < 8; ++r) {
            float4 a = *(const float4*)&Al[(rg + r) * DIM + k];
            acc[r].x += a.x * w0.x + a.y * w1.x + a.z * w2.x + a.w * w3.x;
            acc[r].y += a.x * w0.y + a.y * w1.y + a.z * w2.y + a.w * w3.y;
            acc[r].z += a.x * w0.z + a.y * w1.z + a.z * w2.z + a.w * w3.z;
            acc[r].w += a.x * w0.w + a.y * w1.w + a.z * w2.w + a.w * w3.w;
        }
    }

    float4 b = *(const float4*)&bias[cg];
    #pragma unroll
    for (int r = 0; r < 8; ++r) {
        int row = rg + r;
        if (row < ntile) {
            float4 v;
            v.x = fmaxf(acc[r].x + b.x, 0.f);
            v.y = fmaxf(acc[r].y + b.y, 0.f);
            v.z = fmaxf(acc[r].z + b.z, 0.f);
            v.w = fmaxf(acc[r].w + b.w, 0.f);
            *(float4*)&Cout[(size_t)(row0 + row) * DIM + cg] = v;
        }
    }
}

// ---------------- GraphNorm stats (one pass): mean + var via E[z^2] ----------------
// var = E[(z - s*m)^2] = E[z^2] - (2 - s)*s*m^2   (since E[z] = m)
__global__ __launch_bounds__(256) void gn_stats(const float* __restrict__ z, const int* __restrict__ gstart,
                                                const float* __restrict__ scale, const float* __restrict__ weight,
                                                float* __restrict__ a_sub, float* __restrict__ b_mul) {
    int g = blockIdx.x;
    int d = threadIdx.x & 127;
    int half = threadIdx.x >> 7;
    int s = gstart[g], e = gstart[g + 1];
    float s1 = 0.f, s2 = 0.f;
    for (int n = s + half; n < e; n += 2) {
        float v = z[(size_t)n * DIM + d];
        s1 += v;
        s2 += v * v;
    }
    __shared__ float sh1[256], sh2[256];
    sh1[threadIdx.x] = s1;
    sh2[threadIdx.x] = s2;
    __syncthreads();
    if (half == 0) {
        s1 += sh1[threadIdx.x + 128];
        s2 += sh2[threadIdx.x + 128];
        int cnt = e - s;
        float cf = (float)(cnt > 0 ? cnt : 1);
        float m = s1 / cf;
        float ez2 = s2 / cf;
        float sc = scale[d];
        float var = ez2 - (2.0f - sc) * sc * m * m;
        float inv = 1.0f / sqrtf(var + GN_EPS);
        a_sub[g * DIM + d] = m * sc;
        b_mul[g * DIM + d] = weight[d] * inv;
    }
}

// ---------------- GraphNorm apply + relu ----------------
__global__ __launch_bounds__(256) void gn_apply(const float* __restrict__ z, const int* __restrict__ batch,
                                                const float* __restrict__ a_sub, const float* __restrict__ b_mul,
                                                const float* __restrict__ bias, float* __restrict__ out) {
    int gid = blockIdx.x * 256 + threadIdx.x;  // over N_NODES * 32 float4 groups
    if (gid >= N_NODES * (DIM / 4)) return;
    int row = gid >> 5;
    int c4 = (gid & 31) * 4;
    int g = batch[row];
    float4 v = *(const float4*)&z[(size_t)row * DIM + c4];
    const float* as = &a_sub[g * DIM + c4];
    const float* bm = &b_mul[g * DIM + c4];
    const float* bi = &bias[c4];
    float4 o;
    o.x = fmaxf((v.x - as[0]) * bm[0] + bi[0], 0.f);
    o.y = fmaxf((v.y - as[1]) * bm[1] + bi[1], 0.f);
    o.z = fmaxf((v.z - as[2]) * bm[2] + bi[2], 0.f);
    o.w = fmaxf((v.w - as[3]) * bm[3] + bi[3], 0.f);
    *(float4*)&out[(size_t)row * DIM + c4] = o;
}

// ---------------- per-graph sum readout ----------------
__global__ __launch_bounds__(256) void readout_sum(const float* __restrict__ h, const int* __restrict__ gstart,
                                                   float* __restrict__ gsum) {
    int g = blockIdx.x;
    int d = threadIdx.x & 127;
    int half = threadIdx.x >> 7;
    int s = gstart[g], e = gstart[g + 1];
    float s1 = 0.f;
    for (int n = s + half; n < e; n += 2) s1 += h[(size_t)n * DIM + d];
    __shared__ float sh1[256];
    sh1[threadIdx.x] = s1;
    __syncthreads();
    if (half == 0) gsum[g * DIM + d] = s1 + sh1[threadIdx.x + 128];
}

// ---------------- final MLP + log_softmax, one block per graph ----------------
__global__ __launch_bounds__(128) void final_mlp(const float* __restrict__ gsum,
                                                 const float* __restrict__ fw1, const float* __restrict__ fb1,
                                                 const float* __restrict__ fw2, const float* __restrict__ fb2,
                                                 const float* __restrict__ fw3, const float* __restrict__ fb3,
                                                 float* __restrict__ out) {
    __shared__ float v0[128], v1[128], v2[128], lg[10];
    int t = threadIdx.x;
    int g = blockIdx.x;
    v0[t] = gsum[g * DIM + t];
    __syncthreads();
    float acc = fb1[t];
    for (int d = 0; d < 128; ++d) acc += v0[d] * fw1[d * 128 + t];
    v1[t] = fmaxf(acc, 0.f);
    __syncthreads();
    acc = fb2[t];
    for (int d = 0; d < 128; ++d) acc += v1[d] * fw2[d * 128 + t];
    v2[t] = fmaxf(acc, 0.f);
    __syncthreads();
    if (t < 10) {
        acc = fb3[t];
        for (int d = 0; d < 128; ++d) acc += v2[d] * fw3[d * 10 + t];
        lg[t] = acc;
    }
    __syncthreads();
    if (t < 10) {
        float m = -1e30f;
        for (int c = 0; c < 10; ++c) m = fmaxf(m, lg[c]);
        float ssum = 0.f;
        for (int c = 0; c < 10; ++c) ssum += expf(lg[c] - m);
        out[g * 10 + t] = lg[t] - m - logf(ssum);
    }
}

extern "C" void kernel_launch(void* const* d_in, const int* in_sizes, int n_in,
                              void* d_out, int out_size, void* d_ws, size_t ws_size,
                              hipStream_t stream) {
    const float* x       = (const float*)d_in[0];
    const float* gin_w1  = (const float*)d_in[1];
    const float* gin_b1  = (const float*)d_in[2];
    const float* gin_w2  = (const float*)d_in[3];
    const float* gin_b2  = (const float*)d_in[4];
    const float* gn_w    = (const float*)d_in[5];
    const float* gn_b    = (const float*)d_in[6];
    const float* gn_s    = (const float*)d_in[7];
    const float* fw1     = (const float*)d_in[8];
    const float* fb1     = (const float*)d_in[9];
    const float* fw2     = (const float*)d_in[10];
    const float* fb2     = (const float*)d_in[11];
    const float* fw3     = (const float*)d_in[12];
    const float* fb3     = (const float*)d_in[13];
    const int*   eidx    = (const int*)d_in[14];
    const int*   batch   = (const int*)d_in[15];
    float* out = (float*)d_out;

    const int* esrc = eidx;
    const int* edst = eidx + N_EDGES;

    // ---- workspace layout ----
    char* p = (char*)d_ws;
    float* H = (float*)p;            p += (size_t)N_NODES * DIM * 4;
    float* A = (float*)p;            p += (size_t)N_NODES * DIM * 4;
    float* B = (float*)p;            p += (size_t)N_NODES * DIM * 4;
    float* a_sub = (float*)p;        p += N_GRAPHS * DIM * 4;
    float* b_mul = (float*)p;        p += N_GRAPHS * DIM * 4;
    float* gsum = (float*)p;         p += N_GRAPHS * DIM * 4;
    int* deg = (int*)p;              p += N_NODES * 4;
    int* cursor = (int*)p;           p += N_NODES * 4;
    int* gcnt = (int*)p;             p += N_GRAPHS * 4;
    int* eoff = (int*)p;             p += (N_NODES + 1) * 4;
    int* gstart = (int*)p;           p += (N_GRAPHS + 1) * 4;
    int* csr = (int*)p;              p += (size_t)N_EDGES * 4;

    // zero the counters (deg, cursor, gcnt are contiguous)
    hipMemsetAsync(deg, 0, (size_t)(N_NODES + N_NODES + N_GRAPHS) * 4, stream);

    // ---- build CSR (edges by dst) and graph offsets ----
    edge_hist<<<(N_EDGES + 255) / 256, 256, 0, stream>>>(edst, deg);
    node_hist<<<(N_NODES + 255) / 256, 256, 0, stream>>>(batch, gcnt);
    scan_excl<<<1, 1024, 0, stream>>>(deg, eoff, N_NODES);
    scan_excl<<<1, 1024, 0, stream>>>(gcnt, gstart, N_GRAPHS);
    scatter_edges<<<(N_EDGES + 255) / 256, 256, 0, stream>>>(esrc, edst, eoff, cursor, csr);

    const int mm_grid = (N_NODES + MM_ROWS - 1) / MM_ROWS;
    const float* hcur = x;
    for (int l = 0; l < N_LAYERS; ++l) {
        agg_add<<<(N_NODES + 3) / 4, 256, 0, stream>>>(hcur, eoff, csr, A);
        mm_relu<<<mm_grid, 256, 0, stream>>>(A, gin_w1 + (size_t)l * DIM * DIM, gin_b1 + l * DIM, B, N_NODES);
        mm_relu<<<mm_grid, 256, 0, stream>>>(B, gin_w2 + (size_t)l * DIM * DIM, gin_b2 + l * DIM, A, N_NODES);
        gn_stats<<<N_GRAPHS, 256, 0, stream>>>(A, gstart, gn_s + l * DIM, gn_w + l * DIM, a_sub, b_mul);
        gn_apply<<<(N_NODES * (DIM / 4) + 255) / 256, 256, 0, stream>>>(A, batch, a_sub, b_mul, gn_b + l * DIM, H);
        hcur = H;
    }

    readout_sum<<<N_GRAPHS, 256, 0, stream>>>(H, gstart, gsum);
    final_mlp<<<N_GRAPHS, 128, 0, stream>>>(gsum, fw1, fb1, fw2, fb2, fw3, fb3, out);
}

// Round 2
// 1038.267 us; speedup vs baseline: 1.4059x; 1.4059x over previous
//
#include <hip/hip_runtime.h>
#include <cstddef>

#define N_NODES 50000
#define N_EDGES 800000
#define N_GRAPHS 128
#define DIM 128
#define N_LAYERS 4
#define GN_EPS 1e-5f

typedef unsigned short ushort_t;
typedef __attribute__((ext_vector_type(8))) short frag8;
typedef __attribute__((ext_vector_type(4))) float f32x4;

// round-to-nearest-even bf16 split: v ~= hi + lo (each bf16), error ~2^-17 rel
__device__ inline void bf16split(float v, ushort_t& h, ushort_t& l) {
    unsigned u = __float_as_uint(v);
    unsigned r = u + 0x7fff + ((u >> 16) & 1);
    ushort_t hi = (ushort_t)(r >> 16);
    float fh = __uint_as_float(((unsigned)hi) << 16);
    float rem = v - fh;
    unsigned u2 = __float_as_uint(rem);
    unsigned r2 = u2 + 0x7fff + ((u2 >> 16) & 1);
    l = (ushort_t)(r2 >> 16);
    h = hi;
}

// ---------------- edge degree histogram ----------------
__global__ __launch_bounds__(256) void edge_hist(const int* __restrict__ dst, int* __restrict__ deg) {
    int e = blockIdx.x * 256 + threadIdx.x;
    if (e < N_EDGES) atomicAdd(&deg[dst[e]], 1);
}

// ---------------- graph boundaries from SORTED batch (no atomics) ----------------
__global__ __launch_bounds__(256) void graph_bounds(const int* __restrict__ batch, int* __restrict__ gstart) {
    int i = blockIdx.x * 256 + threadIdx.x;
    if (i >= N_NODES) return;
    int b = batch[i];
    if (i == 0) {
        for (int g = 0; g <= b; ++g) gstart[g] = 0;
    } else {
        int pb = batch[i - 1];
        for (int g = pb + 1; g <= b; ++g) gstart[g] = i;
    }
    if (i == N_NODES - 1) {
        for (int g = b + 1; g <= N_GRAPHS; ++g) gstart[g] = N_NODES;
    }
}

// ---------------- shuffle-based exclusive scan (1 block, 1024 thr, 3 barriers/chunk) ----------------
__global__ __launch_bounds__(1024) void scan_excl(const int* __restrict__ in, int* __restrict__ out, int n) {
    __shared__ int wsum[16];
    __shared__ int carry_s;
    int tid = threadIdx.x, lane = tid & 63, w = tid >> 6;
    if (tid == 0) carry_s = 0;
    __syncthreads();
    for (int base = 0; base < n; base += 1024) {
        int v = (base + tid < n) ? in[base + tid] : 0;
        int s = v;
        #pragma unroll
        for (int off = 1; off < 64; off <<= 1) {
            int t = __shfl_up(s, off, 64);
            if (lane >= off) s += t;
        }
        if (lane == 63) wsum[w] = s;
        int carry = carry_s;
        __syncthreads();
        if (w == 0) {
            int ws = (lane < 16) ? wsum[lane] : 0;
            #pragma unroll
            for (int off = 1; off < 16; off <<= 1) {
                int t = __shfl_up(ws, off, 64);
                if (lane >= off) ws += t;
            }
            if (lane < 16) wsum[lane] = ws;
            if (lane == 15) carry_s = carry + ws;
        }
        __syncthreads();
        int woff = (w > 0) ? wsum[w - 1] : 0;
        if (base + tid < n) out[base + tid] = carry + woff + s - v;
        __syncthreads();
    }
    if (tid == 0) out[n] = carry_s;
}

// ---------------- CSR scatter ----------------
__global__ __launch_bounds__(256) void scatter_edges(const int* __restrict__ src, const int* __restrict__ dst,
                                                     const int* __restrict__ eoff, int* __restrict__ cursor,
                                                     int* __restrict__ csr) {
    int e = blockIdx.x * 256 + threadIdx.x;
    if (e < N_EDGES) {
        int d = dst[e];
        int pos = atomicAdd(&cursor[d], 1);
        csr[eoff[d] + pos] = src[e];
    }
}

// ---------------- weight convert: fp32 W[k][n] -> bf16 hi/lo, TRANSPOSED [n][k] ----------------
__global__ __launch_bounds__(256) void convert_w(const float* __restrict__ w1, const float* __restrict__ w2,
                                                 ushort_t* __restrict__ hi, ushort_t* __restrict__ lo) {
    int idx = blockIdx.x * 256 + threadIdx.x;  // 8 * 16384
    if (idx >= 8 * DIM * DIM) return;
    int mat = idx >> 14;
    int e = idx & 16383;
    int n = e >> 7, k = e & 127;
    int l = mat >> 1;
    const float* src = (mat & 1) ? (w2 + (size_t)l * DIM * DIM) : (w1 + (size_t)l * DIM * DIM);
    float v = src[k * DIM + n];
    ushort_t h, lw;
    bf16split(v, h, lw);
    hi[(size_t)mat * DIM * DIM + n * DIM + k] = h;
    lo[(size_t)mat * DIM * DIM + n * DIM + k] = lw;
}

// ---------------- GIN aggregation: t = h + sum_{j->i} h_j, output split bf16 hi/lo ----------------
__global__ __launch_bounds__(256) void agg_add_split(const float* __restrict__ h, const int* __restrict__ eoff,
                                                     const int* __restrict__ csr,
                                                     ushort_t* __restrict__ o_hi, ushort_t* __restrict__ o_lo) {
    int wid = (blockIdx.x * 256 + threadIdx.x) >> 6;
    int lane = threadIdx.x & 63;
    if (wid >= N_NODES) return;
    int lo = eoff[wid], hi = eoff[wid + 1];
    const float* hr = h + (size_t)wid * DIM;
    float a0 = hr[lane];
    float a1 = hr[lane + 64];
    for (int e = lo; e < hi; ++e) {
        int j = csr[e];
        const float* hj = h + (size_t)j * DIM;
        a0 += hj[lane];
        a1 += hj[lane + 64];
    }
    ushort_t h0, l0, h1, l1;
    bf16split(a0, h0, l0);
    bf16split(a1, h1, l1);
    size_t base = (size_t)wid * DIM;
    o_hi[base + lane] = h0;
    o_hi[base + lane + 64] = h1;
    o_lo[base + lane] = l0;
    o_lo[base + lane + 64] = l1;
}

// ---------------- MFMA GEMM: C = relu(A @ W + b), A[n,128] as bf16 hi/lo, W transposed [n][k] hi/lo ----
// C = Ah@Wh + Ah@Wl + Al@Wh (fp32 accumulate). 128 rows x 128 cols per block, 4 waves.
// LDS XOR-swizzle: chunk c (8 ushorts) of row r stored at chunk (c ^ (r&7)).
template<bool SPLIT_OUT>
__global__ __launch_bounds__(256) void mm_mfma(const ushort_t* __restrict__ Ahi, const ushort_t* __restrict__ Alo,
                                               const ushort_t* __restrict__ Whi, const ushort_t* __restrict__ Wlo,
                                               const float* __restrict__ bias,
                                               float* __restrict__ Cf,
                                               ushort_t* __restrict__ Chi, ushort_t* __restrict__ Clo) {
    __shared__ ushort_t As[128 * 128];
    __shared__ ushort_t Ws[128 * 128];
    int tid = threadIdx.x;
    int row0 = blockIdx.x * 128;
    int wave = tid >> 6, lane = tid & 63;
    int q = lane >> 4, mn = lane & 15;

    f32x4 acc[2][8];
    #pragma unroll
    for (int t = 0; t < 2; ++t)
        #pragma unroll
        for (int n = 0; n < 8; ++n) acc[t][n] = (f32x4)(0.f);

    auto stageA = [&](const ushort_t* src) {
        #pragma unroll
        for (int i = 0; i < 8; ++i) {
            int c = tid + i * 256;
            int r = c >> 4, c8 = c & 15;
            uint4 v = make_uint4(0u, 0u, 0u, 0u);
            int gr = row0 + r;
            if (gr < N_NODES) v = *(const uint4*)(src + (size_t)gr * DIM + c8 * 8);
            *(uint4*)(&As[r * 128 + (c8 ^ (r & 7)) * 8]) = v;
        }
    };
    auto stageW = [&](const ushort_t* src) {
        #pragma unroll
        for (int i = 0; i < 8; ++i) {
            int c = tid + i * 256;
            int r = c >> 4, c8 = c & 15;
            uint4 v = *(const uint4*)(src + r * DIM + c8 * 8);
            *(uint4*)(&Ws[r * 128 + (c8 ^ (r & 7)) * 8]) = v;
        }
    };
    auto compute = [&]() {
        #pragma unroll
        for (int ks = 0; ks < 4; ++ks) {
            int m0 = wave * 32 + mn;
            int m1 = m0 + 16;
            frag8 a0 = *(const frag8*)&As[m0 * 128 + (((ks * 4 + q) ^ (m0 & 7)) * 8)];
            frag8 a1 = *(const frag8*)&As[m1 * 128 + (((ks * 4 + q) ^ (m1 & 7)) * 8)];
            #pragma unroll
            for (int n = 0; n < 8; ++n) {
                int nr = n * 16 + mn;
                frag8 b = *(const frag8*)&Ws[nr * 128 + (((ks * 4 + q) ^ (nr & 7)) * 8)];
                acc[0][n] = __builtin_amdgcn_mfma_f32_16x16x32_bf16(a0, b, acc[0][n], 0, 0, 0);
                acc[1][n] = __builtin_amdgcn_mfma_f32_16x16x32_bf16(a1, b, acc[1][n], 0, 0, 0);
            }
        }
    };

    stageA(Ahi); stageW(Whi);
    __syncthreads(); compute(); __syncthreads();
    stageW(Wlo);
    __syncthreads(); compute(); __syncthreads();
    stageA(Alo); stageW(Whi);
    __syncthreads(); compute();

    // epilogue: C/D layout col=lane&15, row=(lane>>4)*4+reg
    int mbase = row0 + wave * 32;
    #pragma unroll
    for (int t = 0; t < 2; ++t) {
        #pragma unroll
        for (int n = 0; n < 8; ++n) {
            int col = n * 16 + mn;
            float bv = bias[col];
            #pragma unroll
            for (int r = 0; r < 4; ++r) {
                int grow = mbase + t * 16 + q * 4 + r;
                if (grow < N_NODES) {
                    float v = fmaxf(acc[t][n][r] + bv, 0.f);
                    if (SPLIT_OUT) {
                        ushort_t h, l;
                        bf16split(v, h, l);
                        Chi[(size_t)grow * DIM + col] = h;
                        Clo[(size_t)grow * DIM + col] = l;
                    } else {
                        Cf[(size_t)grow * DIM + col] = v;
                    }
                }
            }
        }
    }
}

// ---------------- GraphNorm stats: var = E[z^2] - (2-s)*s*m^2 ----------------
__global__ __launch_bounds__(256) void gn_stats(const float* __restrict__ z, const int* __restrict__ gstart,
                                                const float* __restrict__ scale, const float* __restrict__ weight,
                                                float* __restrict__ a_sub, float* __restrict__ b_mul) {
    int g = blockIdx.x;
    int d = threadIdx.x & 127;
    int half = threadIdx.x >> 7;
    int s = gstart[g], e = gstart[g + 1];
    float s1 = 0.f, s2 = 0.f;
    for (int n = s + half; n < e; n += 2) {
        float v = z[(size_t)n * DIM + d];
        s1 += v;
        s2 += v * v;
    }
    __shared__ float sh1[256], sh2[256];
    sh1[threadIdx.x] = s1;
    sh2[threadIdx.x] = s2;
    __syncthreads();
    if (half == 0) {
        s1 += sh1[threadIdx.x + 128];
        s2 += sh2[threadIdx.x + 128];
        int cnt = e - s;
        float cf = (float)(cnt > 0 ? cnt : 1);
        float m = s1 / cf;
        float ez2 = s2 / cf;
        float sc = scale[d];
        float var = ez2 - (2.0f - sc) * sc * m * m;
        float inv = 1.0f / sqrtf(var + GN_EPS);
        a_sub[g * DIM + d] = m * sc;
        b_mul[g * DIM + d] = weight[d] * inv;
    }
}

// ---------------- GraphNorm apply + relu (fp32 out) ----------------
__global__ __launch_bounds__(256) void gn_apply(const float* __restrict__ z, const int* __restrict__ batch,
                                                const float* __restrict__ a_sub, const float* __restrict__ b_mul,
                                                const float* __restrict__ bias, float* __restrict__ out) {
    int gid = blockIdx.x * 256 + threadIdx.x;
    if (gid >= N_NODES * (DIM / 4)) return;
    int row = gid >> 5;
    int c4 = (gid & 31) * 4;
    int g = batch[row];
    float4 v = *(const float4*)&z[(size_t)row * DIM + c4];
    const float* as = &a_sub[g * DIM + c4];
    const float* bm = &b_mul[g * DIM + c4];
    const float* bi = &bias[c4];
    float4 o;
    o.x = fmaxf((v.x - as[0]) * bm[0] + bi[0], 0.f);
    o.y = fmaxf((v.y - as[1]) * bm[1] + bi[1], 0.f);
    o.z = fmaxf((v.z - as[2]) * bm[2] + bi[2], 0.f);
    o.w = fmaxf((v.w - as[3]) * bm[3] + bi[3], 0.f);
    *(float4*)&out[(size_t)row * DIM + c4] = o;
}

// ---------------- per-graph sum readout ----------------
__global__ __launch_bounds__(256) void readout_sum(const float* __restrict__ h, const int* __restrict__ gstart,
                                                   float* __restrict__ gsum) {
    int g = blockIdx.x;
    int d = threadIdx.x & 127;
    int half = threadIdx.x >> 7;
    int s = gstart[g], e = gstart[g + 1];
    float s1 = 0.f;
    for (int n = s + half; n < e; n += 2) s1 += h[(size_t)n * DIM + d];
    __shared__ float sh1[256];
    sh1[threadIdx.x] = s1;
    __syncthreads();
    if (half == 0) gsum[g * DIM + d] = s1 + sh1[threadIdx.x + 128];
}

// ---------------- final MLP + log_softmax ----------------
__global__ __launch_bounds__(128) void final_mlp(const float* __restrict__ gsum,
                                                 const float* __restrict__ fw1, const float* __restrict__ fb1,
                                                 const float* __restrict__ fw2, const float* __restrict__ fb2,
                                                 const float* __restrict__ fw3, const float* __restrict__ fb3,
                                                 float* __restrict__ out) {
    __shared__ float v0[128], v1[128], v2[128], lg[10];
    int t = threadIdx.x;
    int g = blockIdx.x;
    v0[t] = gsum[g * DIM + t];
    __syncthreads();
    float acc = fb1[t];
    for (int d = 0; d < 128; ++d) acc += v0[d] * fw1[d * 128 + t];
    v1[t] = fmaxf(acc, 0.f);
    __syncthreads();
    acc = fb2[t];
    for (int d = 0; d < 128; ++d) acc += v1[d] * fw2[d * 128 + t];
    v2[t] = fmaxf(acc, 0.f);
    __syncthreads();
    if (t < 10) {
        acc = fb3[t];
        for (int d = 0; d < 128; ++d) acc += v2[d] * fw3[d * 10 + t];
        lg[t] = acc;
    }
    __syncthreads();
    if (t < 10) {
        float m = -1e30f;
        for (int c = 0; c < 10; ++c) m = fmaxf(m, lg[c]);
        float ssum = 0.f;
        for (int c = 0; c < 10; ++c) ssum += expf(lg[c] - m);
        out[g * 10 + t] = lg[t] - m - logf(ssum);
    }
}

extern "C" void kernel_launch(void* const* d_in, const int* in_sizes, int n_in,
                              void* d_out, int out_size, void* d_ws, size_t ws_size,
                              hipStream_t stream) {
    const float* x      = (const float*)d_in[0];
    const float* gin_w1 = (const float*)d_in[1];
    const float* gin_b1 = (const float*)d_in[2];
    const float* gin_w2 = (const float*)d_in[3];
    const float* gin_b2 = (const float*)d_in[4];
    const float* gn_w   = (const float*)d_in[5];
    const float* gn_b   = (const float*)d_in[6];
    const float* gn_s   = (const float*)d_in[7];
    const float* fw1    = (const float*)d_in[8];
    const float* fb1    = (const float*)d_in[9];
    const float* fw2    = (const float*)d_in[10];
    const float* fb2    = (const float*)d_in[11];
    const float* fw3    = (const float*)d_in[12];
    const float* fb3    = (const float*)d_in[13];
    const int*   eidx   = (const int*)d_in[14];
    const int*   batch  = (const int*)d_in[15];
    float* out = (float*)d_out;

    const int* esrc = eidx;
    const int* edst = eidx + N_EDGES;

    // ---- workspace layout (256B-aligned chunks) ----
    auto align_up = [](size_t v) { return (v + 255) & ~(size_t)255; };
    char* p = (char*)d_ws;
    float* H = (float*)p;        p += align_up((size_t)N_NODES * DIM * 4);
    ushort_t* Thi = (ushort_t*)p;  // Thi+Tlo contiguous; Zf aliases this block after mm1 consumes T
    ushort_t* Tlo = Thi + (size_t)N_NODES * DIM;
    float* Zf = (float*)Thi;
    p += align_up((size_t)N_NODES * DIM * 4);
    ushort_t* Z1hi = (ushort_t*)p; p += align_up((size_t)N_NODES * DIM * 2);
    ushort_t* Z1lo = (ushort_t*)p; p += align_up((size_t)N_NODES * DIM * 2);
    ushort_t* WThi = (ushort_t*)p; p += align_up((size_t)8 * DIM * DIM * 2);
    ushort_t* WTlo = (ushort_t*)p; p += align_up((size_t)8 * DIM * DIM * 2);
    float* a_sub = (float*)p;    p += align_up(N_GRAPHS * DIM * 4);
    float* b_mul = (float*)p;    p += align_up(N_GRAPHS * DIM * 4);
    float* gsum = (float*)p;     p += align_up(N_GRAPHS * DIM * 4);
    int* deg = (int*)p;          p += align_up(N_NODES * 4);
    int* cursor = (int*)p;       p += align_up(N_NODES * 4);
    int* eoff = (int*)p;         p += align_up((N_NODES + 1) * 4);
    int* gstart = (int*)p;       p += align_up((N_GRAPHS + 1) * 4);
    int* csr = (int*)p;          p += align_up((size_t)N_EDGES * 4);

    hipMemsetAsync(deg, 0, align_up(N_NODES * 4) + N_NODES * 4, stream);  // deg + cursor

    edge_hist<<<(N_EDGES + 255) / 256, 256, 0, stream>>>(edst, deg);
    graph_bounds<<<(N_NODES + 255) / 256, 256, 0, stream>>>(batch, gstart);
    scan_excl<<<1, 1024, 0, stream>>>(deg, eoff, N_NODES);
    scatter_edges<<<(N_EDGES + 255) / 256, 256, 0, stream>>>(esrc, edst, eoff, cursor, csr);
    convert_w<<<(8 * DIM * DIM + 255) / 256, 256, 0, stream>>>(gin_w1, gin_w2, WThi, WTlo);

    const int mm_grid = (N_NODES + 127) / 128;
    const float* hcur = x;
    for (int l = 0; l < N_LAYERS; ++l) {
        agg_add_split<<<(N_NODES + 3) / 4, 256, 0, stream>>>(hcur, eoff, csr, Thi, Tlo);
        mm_mfma<true><<<mm_grid, 256, 0, stream>>>(Thi, Tlo,
            WThi + (size_t)(2 * l) * DIM * DIM, WTlo + (size_t)(2 * l) * DIM * DIM,
            gin_b1 + l * DIM, nullptr, Z1hi, Z1lo);
        mm_mfma<false><<<mm_grid, 256, 0, stream>>>(Z1hi, Z1lo,
            WThi + (size_t)(2 * l + 1) * DIM * DIM, WTlo + (size_t)(2 * l + 1) * DIM * DIM,
            gin_b2 + l * DIM, Zf, nullptr, nullptr);
        gn_stats<<<N_GRAPHS, 256, 0, stream>>>(Zf, gstart, gn_s + l * DIM, gn_w + l * DIM, a_sub, b_mul);
        gn_apply<<<(N_NODES * (DIM / 4) + 255) / 256, 256, 0, stream>>>(Zf, batch, a_sub, b_mul, gn_b + l * DIM, H);
        hcur = H;
    }

    readout_sum<<<N_GRAPHS, 256, 0, stream>>>(H, gstart, gsum);
    final_mlp<<<N_GRAPHS, 128, 0, stream>>>(gsum, fw1, fb1, fw2, fb2, fw3, fb3, out);
}

// Round 3
// 582.768 us; speedup vs baseline: 2.5048x; 1.7816x over previous
//
#include <hip/hip_runtime.h>
#include <cstddef>

#define N_NODES 50000
#define N_EDGES 800000
#define N_GRAPHS 128
#define DIM 128
#define N_LAYERS 4
#define GN_EPS 1e-5f

typedef unsigned short ushort_t;
typedef __attribute__((ext_vector_type(8))) short frag8;
typedef __attribute__((ext_vector_type(4))) float f32x4;

__device__ inline float bfbits2f(unsigned hi16) { return __uint_as_float(hi16 << 16); }
__device__ inline ushort_t bf16rne(float v) {
    unsigned u = __float_as_uint(v);
    unsigned r = u + 0x7fff + ((u >> 16) & 1);
    return (ushort_t)(r >> 16);
}
// split: v ~= hi + lo, each bf16 (for weights)
__device__ inline void bf16split(float v, ushort_t& h, ushort_t& l) {
    ushort_t hi = bf16rne(v);
    float fh = __uint_as_float(((unsigned)hi) << 16);
    l = bf16rne(v - fh);
    h = hi;
}

// ---------------- edge degree histogram ----------------
__global__ __launch_bounds__(256) void edge_hist(const int* __restrict__ dst, int* __restrict__ deg) {
    int e = blockIdx.x * 256 + threadIdx.x;
    if (e < N_EDGES) atomicAdd(&deg[dst[e]], 1);
}

// ---------------- graph boundaries from SORTED batch ----------------
__global__ __launch_bounds__(256) void graph_bounds(const int* __restrict__ batch, int* __restrict__ gstart) {
    int i = blockIdx.x * 256 + threadIdx.x;
    if (i >= N_NODES) return;
    int b = batch[i];
    if (i == 0) {
        for (int g = 0; g <= b; ++g) gstart[g] = 0;
    } else {
        int pb = batch[i - 1];
        for (int g = pb + 1; g <= b; ++g) gstart[g] = i;
    }
    if (i == N_NODES - 1) {
        for (int g = b + 1; g <= N_GRAPHS; ++g) gstart[g] = N_NODES;
    }
}

// ---------------- 3-phase scan ----------------
__global__ __launch_bounds__(1024) void scan_local(const int* __restrict__ in, int* __restrict__ out,
                                                   int* __restrict__ bsum, int n) {
    __shared__ int wsum[16];
    int tid = threadIdx.x, lane = tid & 63, w = tid >> 6;
    int gi = blockIdx.x * 1024 + tid;
    int v = (gi < n) ? in[gi] : 0;
    int s = v;
    #pragma unroll
    for (int off = 1; off < 64; off <<= 1) {
        int t = __shfl_up(s, off, 64);
        if (lane >= off) s += t;
    }
    if (lane == 63) wsum[w] = s;
    __syncthreads();
    if (w == 0) {
        int ws = (lane < 16) ? wsum[lane] : 0;
        #pragma unroll
        for (int off = 1; off < 16; off <<= 1) {
            int t = __shfl_up(ws, off, 64);
            if (lane >= off) ws += t;
        }
        if (lane < 16) wsum[lane] = ws;
    }
    __syncthreads();
    int woff = (w > 0) ? wsum[w - 1] : 0;
    if (gi < n) out[gi] = woff + s - v;
    if (tid == 1023) bsum[blockIdx.x] = woff + s;
}

__global__ __launch_bounds__(64) void scan_block(int* __restrict__ bsum, int nb) {
    int lane = threadIdx.x;
    int v = (lane < nb) ? bsum[lane] : 0;
    int s = v;
    #pragma unroll
    for (int off = 1; off < 64; off <<= 1) {
        int t = __shfl_up(s, off, 64);
        if (lane >= off) s += t;
    }
    if (lane < nb) bsum[lane] = s - v;  // exclusive
}

__global__ __launch_bounds__(1024) void scan_add(int* __restrict__ out, const int* __restrict__ bsum, int n, int total) {
    int gi = blockIdx.x * 1024 + threadIdx.x;
    if (gi < n) out[gi] += bsum[blockIdx.x];
    if (blockIdx.x == 0 && threadIdx.x == 0) out[n] = total;
}

// ---------------- CSR scatter ----------------
__global__ __launch_bounds__(256) void scatter_edges(const int* __restrict__ src, const int* __restrict__ dst,
                                                     const int* __restrict__ eoff, int* __restrict__ cursor,
                                                     int* __restrict__ csr) {
    int e = blockIdx.x * 256 + threadIdx.x;
    if (e < N_EDGES) {
        int d = dst[e];
        int pos = atomicAdd(&cursor[d], 1);
        csr[eoff[d] + pos] = src[e];
    }
}

// ---------------- weight convert: fp32 W[k][n] -> bf16 hi/lo, TRANSPOSED [n][k] ----------------
__global__ __launch_bounds__(256) void convert_w(const float* __restrict__ w1, const float* __restrict__ w2,
                                                 ushort_t* __restrict__ hi, ushort_t* __restrict__ lo) {
    int idx = blockIdx.x * 256 + threadIdx.x;
    if (idx >= 8 * DIM * DIM) return;
    int mat = idx >> 14;
    int e = idx & 16383;
    int n = e >> 7, k = e & 127;
    int l = mat >> 1;
    const float* src = (mat & 1) ? (w2 + (size_t)l * DIM * DIM) : (w1 + (size_t)l * DIM * DIM);
    float v = src[k * DIM + n];
    ushort_t h, lw;
    bf16split(v, h, lw);
    hi[(size_t)mat * DIM * DIM + n * DIM + k] = h;
    lo[(size_t)mat * DIM * DIM + n * DIM + k] = lw;
}

// ---------------- x -> bf16 packed ----------------
__global__ __launch_bounds__(256) void convert_x(const float* __restrict__ x, unsigned* __restrict__ Hb) {
    int i = blockIdx.x * 256 + threadIdx.x;  // over N_NODES*64 uints
    if (i >= N_NODES * 64) return;
    float a = x[2 * i], b = x[2 * i + 1];
    Hb[i] = (unsigned)bf16rne(a) | ((unsigned)bf16rne(b) << 16);
}

// ---------------- GIN aggregation on bf16 h: T = h + sum_{j->i} h_j ----------------
// one wave per node; lane owns packed elems [2*lane, 2*lane+1]
__global__ __launch_bounds__(256) void agg_bf16(const unsigned* __restrict__ h, const int* __restrict__ eoff,
                                                const int* __restrict__ csr, unsigned* __restrict__ T) {
    int wid = (blockIdx.x * 256 + threadIdx.x) >> 6;
    int lane = threadIdx.x & 63;
    if (wid >= N_NODES) return;
    int lo = eoff[wid], hi = eoff[wid + 1];
    unsigned v = h[(size_t)wid * 64 + lane];
    float a0 = bfbits2f(v & 0xffffu);
    float a1 = bfbits2f(v >> 16);
    int e = lo;
    for (; e + 3 < hi; e += 4) {
        int j0 = csr[e], j1 = csr[e + 1], j2 = csr[e + 2], j3 = csr[e + 3];
        unsigned v0 = h[(size_t)j0 * 64 + lane];
        unsigned v1 = h[(size_t)j1 * 64 + lane];
        unsigned v2 = h[(size_t)j2 * 64 + lane];
        unsigned v3 = h[(size_t)j3 * 64 + lane];
        a0 += bfbits2f(v0 & 0xffffu) + bfbits2f(v1 & 0xffffu) + bfbits2f(v2 & 0xffffu) + bfbits2f(v3 & 0xffffu);
        a1 += bfbits2f(v0 >> 16) + bfbits2f(v1 >> 16) + bfbits2f(v2 >> 16) + bfbits2f(v3 >> 16);
    }
    for (; e < hi; ++e) {
        unsigned v0 = h[(size_t)csr[e] * 64 + lane];
        a0 += bfbits2f(v0 & 0xffffu);
        a1 += bfbits2f(v0 >> 16);
    }
    T[(size_t)wid * 64 + lane] = (unsigned)bf16rne(a0) | ((unsigned)bf16rne(a1) << 16);
}

// ---------------- MFMA GEMM: C = relu(A @ W + b); A[n,128] bf16, W^T [n][k] hi/lo ----------------
// C = A@Wh + A@Wl, fp32 accumulate. 128x128 per block, 4 waves, XOR-swizzled LDS.
template<bool OUT_BF16>
__global__ __launch_bounds__(256) void mm_mfma(const ushort_t* __restrict__ A,
                                               const ushort_t* __restrict__ Whi, const ushort_t* __restrict__ Wlo,
                                               const float* __restrict__ bias,
                                               float* __restrict__ Cf, ushort_t* __restrict__ Cb) {
    __shared__ ushort_t As[128 * 128];
    __shared__ ushort_t Ws[128 * 128];
    int tid = threadIdx.x;
    int row0 = blockIdx.x * 128;
    int wave = tid >> 6, lane = tid & 63;
    int q = lane >> 4, mn = lane & 15;

    f32x4 acc[2][8];
    #pragma unroll
    for (int t = 0; t < 2; ++t)
        #pragma unroll
        for (int n = 0; n < 8; ++n) acc[t][n] = (f32x4)(0.f);

    // stage A (128 rows x 128 cols bf16)
    #pragma unroll
    for (int i = 0; i < 8; ++i) {
        int c = tid + i * 256;
        int r = c >> 4, c8 = c & 15;
        uint4 v = make_uint4(0u, 0u, 0u, 0u);
        int gr = row0 + r;
        if (gr < N_NODES) v = *(const uint4*)(A + (size_t)gr * DIM + c8 * 8);
        *(uint4*)(&As[r * 128 + (c8 ^ (r & 7)) * 8]) = v;
    }
    auto stageW = [&](const ushort_t* src) {
        #pragma unroll
        for (int i = 0; i < 8; ++i) {
            int c = tid + i * 256;
            int r = c >> 4, c8 = c & 15;
            uint4 v = *(const uint4*)(src + r * DIM + c8 * 8);
            *(uint4*)(&Ws[r * 128 + (c8 ^ (r & 7)) * 8]) = v;
        }
    };
    auto compute = [&]() {
        #pragma unroll
        for (int ks = 0; ks < 4; ++ks) {
            int m0 = wave * 32 + mn;
            int m1 = m0 + 16;
            frag8 a0 = *(const frag8*)&As[m0 * 128 + (((ks * 4 + q) ^ (m0 & 7)) * 8)];
            frag8 a1 = *(const frag8*)&As[m1 * 128 + (((ks * 4 + q) ^ (m1 & 7)) * 8)];
            #pragma unroll
            for (int n = 0; n < 8; ++n) {
                int nr = n * 16 + mn;
                frag8 b = *(const frag8*)&Ws[nr * 128 + (((ks * 4 + q) ^ (nr & 7)) * 8)];
                acc[0][n] = __builtin_amdgcn_mfma_f32_16x16x32_bf16(a0, b, acc[0][n], 0, 0, 0);
                acc[1][n] = __builtin_amdgcn_mfma_f32_16x16x32_bf16(a1, b, acc[1][n], 0, 0, 0);
            }
        }
    };

    stageW(Whi);
    __syncthreads(); compute(); __syncthreads();
    stageW(Wlo);
    __syncthreads(); compute();

    int mbase = row0 + wave * 32;
    #pragma unroll
    for (int t = 0; t < 2; ++t) {
        #pragma unroll
        for (int n = 0; n < 8; ++n) {
            int col = n * 16 + mn;
            float bv = bias[col];
            #pragma unroll
            for (int r = 0; r < 4; ++r) {
                int grow = mbase + t * 16 + q * 4 + r;
                if (grow < N_NODES) {
                    float v = fmaxf(acc[t][n][r] + bv, 0.f);
                    if (OUT_BF16) Cb[(size_t)grow * DIM + col] = bf16rne(v);
                    else          Cf[(size_t)grow * DIM + col] = v;
                }
            }
        }
    }
}

// ---------------- fused GraphNorm: stats + apply(+relu, bf16 out) + optional readout ----------------
// var = E[z^2] - (2-s)*s*m^2  (since E[z] = m); one block per graph, 1024 threads (8 row-groups)
template<bool LAST>
__global__ __launch_bounds__(1024) void gn_fused(const float* __restrict__ Zf, const int* __restrict__ gstart,
                                                 const float* __restrict__ scale, const float* __restrict__ weight,
                                                 const float* __restrict__ bias,
                                                 ushort_t* __restrict__ Hb, float* __restrict__ gsum) {
    __shared__ float sh1[1024], sh2[1024];
    __shared__ float sa[128], sb[128];
    int g = blockIdx.x;
    int d = threadIdx.x & 127, rg = threadIdx.x >> 7;
    int s = gstart[g], e = gstart[g + 1];
    float s1 = 0.f, s2 = 0.f;
    for (int n = s + rg; n < e; n += 8) {
        float v = Zf[(size_t)n * DIM + d];
        s1 += v;
        s2 += v * v;
    }
    sh1[threadIdx.x] = s1;
    sh2[threadIdx.x] = s2;
    __syncthreads();
    if (rg == 0) {
        #pragma unroll
        for (int k = 1; k < 8; ++k) {
            s1 += sh1[d + 128 * k];
            s2 += sh2[d + 128 * k];
        }
        int cnt = e - s;
        float cf = (float)(cnt > 0 ? cnt : 1);
        float m = s1 / cf;
        float ez2 = s2 / cf;
        float sc = scale[d];
        float var = ez2 - (2.0f - sc) * sc * m * m;
        float inv = 1.0f / sqrtf(var + GN_EPS);
        sa[d] = m * sc;
        sb[d] = weight[d] * inv;
    }
    __syncthreads();
    float asub = sa[d], bmul = sb[d], bi = bias[d];
    float rsum = 0.f;
    for (int n = s + rg; n < e; n += 8) {
        float v = Zf[(size_t)n * DIM + d];
        float o = fmaxf((v - asub) * bmul + bi, 0.f);
        if (LAST) rsum += o;
        else Hb[(size_t)n * DIM + d] = bf16rne(o);
    }
    if (LAST) {
        __syncthreads();
        sh1[threadIdx.x] = rsum;
        __syncthreads();
        if (rg == 0) {
            #pragma unroll
            for (int k = 1; k < 8; ++k) rsum += sh1[d + 128 * k];
            gsum[g * DIM + d] = rsum;
        }
    }
}

// ---------------- final MLP + log_softmax ----------------
__global__ __launch_bounds__(128) void final_mlp(const float* __restrict__ gsum,
                                                 const float* __restrict__ fw1, const float* __restrict__ fb1,
                                                 const float* __restrict__ fw2, const float* __restrict__ fb2,
                                                 const float* __restrict__ fw3, const float* __restrict__ fb3,
                                                 float* __restrict__ out) {
    __shared__ float v0[128], v1[128], v2[128], lg[10];
    int t = threadIdx.x;
    int g = blockIdx.x;
    v0[t] = gsum[g * DIM + t];
    __syncthreads();
    float acc = fb1[t];
    for (int d = 0; d < 128; ++d) acc += v0[d] * fw1[d * 128 + t];
    v1[t] = fmaxf(acc, 0.f);
    __syncthreads();
    acc = fb2[t];
    for (int d = 0; d < 128; ++d) acc += v1[d] * fw2[d * 128 + t];
    v2[t] = fmaxf(acc, 0.f);
    __syncthreads();
    if (t < 10) {
        acc = fb3[t];
        for (int d = 0; d < 128; ++d) acc += v2[d] * fw3[d * 10 + t];
        lg[t] = acc;
    }
    __syncthreads();
    if (t < 10) {
        float m = -1e30f;
        for (int c = 0; c < 10; ++c) m = fmaxf(m, lg[c]);
        float ssum = 0.f;
        for (int c = 0; c < 10; ++c) ssum += expf(lg[c] - m);
        out[g * 10 + t] = lg[t] - m - logf(ssum);
    }
}

extern "C" void kernel_launch(void* const* d_in, const int* in_sizes, int n_in,
                              void* d_out, int out_size, void* d_ws, size_t ws_size,
                              hipStream_t stream) {
    const float* x      = (const float*)d_in[0];
    const float* gin_w1 = (const float*)d_in[1];
    const float* gin_b1 = (const float*)d_in[2];
    const float* gin_w2 = (const float*)d_in[3];
    const float* gin_b2 = (const float*)d_in[4];
    const float* gn_w   = (const float*)d_in[5];
    const float* gn_b   = (const float*)d_in[6];
    const float* gn_s   = (const float*)d_in[7];
    const float* fw1    = (const float*)d_in[8];
    const float* fb1    = (const float*)d_in[9];
    const float* fw2    = (const float*)d_in[10];
    const float* fb2    = (const float*)d_in[11];
    const float* fw3    = (const float*)d_in[12];
    const float* fb3    = (const float*)d_in[13];
    const int*   eidx   = (const int*)d_in[14];
    const int*   batch  = (const int*)d_in[15];
    float* out = (float*)d_out;

    const int* esrc = eidx;
    const int* edst = eidx + N_EDGES;

    auto align_up = [](size_t v) { return (v + 255) & ~(size_t)255; };
    char* p = (char*)d_ws;
    unsigned* Hb = (unsigned*)p;   p += align_up((size_t)N_NODES * DIM * 2);  // bf16 h
    unsigned* Tb = (unsigned*)p;   p += align_up((size_t)N_NODES * DIM * 2);  // bf16 agg out
    ushort_t* Z1b = (ushort_t*)p;  p += align_up((size_t)N_NODES * DIM * 2);  // bf16 mm1 out
    float* Zf = (float*)p;         p += align_up((size_t)N_NODES * DIM * 4);  // fp32 mm2 out
    ushort_t* WThi = (ushort_t*)p; p += align_up((size_t)8 * DIM * DIM * 2);
    ushort_t* WTlo = (ushort_t*)p; p += align_up((size_t)8 * DIM * DIM * 2);
    float* gsum = (float*)p;       p += align_up(N_GRAPHS * DIM * 4);
    int* deg = (int*)p;            p += align_up(N_NODES * 4);
    int* cursor = (int*)p;         p += align_up(N_NODES * 4);
    int* eoff = (int*)p;           p += align_up((N_NODES + 1) * 4);
    int* gstart = (int*)p;         p += align_up((N_GRAPHS + 1) * 4);
    int* bsum = (int*)p;           p += align_up(64 * 4);
    int* csr = (int*)p;            p += align_up((size_t)N_EDGES * 4);

    hipMemsetAsync(deg, 0, align_up(N_NODES * 4) + N_NODES * 4, stream);  // deg + cursor

    const int SCAN_BLKS = (N_NODES + 1023) / 1024;  // 49
    edge_hist<<<(N_EDGES + 255) / 256, 256, 0, stream>>>(edst, deg);
    graph_bounds<<<(N_NODES + 255) / 256, 256, 0, stream>>>(batch, gstart);
    scan_local<<<SCAN_BLKS, 1024, 0, stream>>>(deg, eoff, bsum, N_NODES);
    scan_block<<<1, 64, 0, stream>>>(bsum, SCAN_BLKS);
    scan_add<<<SCAN_BLKS, 1024, 0, stream>>>(eoff, bsum, N_NODES, N_EDGES);
    scatter_edges<<<(N_EDGES + 255) / 256, 256, 0, stream>>>(esrc, edst, eoff, cursor, csr);
    convert_w<<<(8 * DIM * DIM + 255) / 256, 256, 0, stream>>>(gin_w1, gin_w2, WThi, WTlo);
    convert_x<<<(N_NODES * 64 + 255) / 256, 256, 0, stream>>>(x, Hb);

    const int mm_grid = (N_NODES + 127) / 128;
    for (int l = 0; l < N_LAYERS; ++l) {
        agg_bf16<<<(N_NODES + 3) / 4, 256, 0, stream>>>(Hb, eoff, csr, Tb);
        mm_mfma<true><<<mm_grid, 256, 0, stream>>>((const ushort_t*)Tb,
            WThi + (size_t)(2 * l) * DIM * DIM, WTlo + (size_t)(2 * l) * DIM * DIM,
            gin_b1 + l * DIM, nullptr, Z1b);
        mm_mfma<false><<<mm_grid, 256, 0, stream>>>(Z1b,
            WThi + (size_t)(2 * l + 1) * DIM * DIM, WTlo + (size_t)(2 * l + 1) * DIM * DIM,
            gin_b2 + l * DIM, Zf, nullptr);
        if (l == N_LAYERS - 1)
            gn_fused<true><<<N_GRAPHS, 1024, 0, stream>>>(Zf, gstart, gn_s + l * DIM, gn_w + l * DIM,
                                                          gn_b + l * DIM, (ushort_t*)Hb, gsum);
        else
            gn_fused<false><<<N_GRAPHS, 1024, 0, stream>>>(Zf, gstart, gn_s + l * DIM, gn_w + l * DIM,
                                                           gn_b + l * DIM, (ushort_t*)Hb, gsum);
    }

    final_mlp<<<N_GRAPHS, 128, 0, stream>>>(gsum, fw1, fb1, fw2, fb2, fw3, fb3, out);
}